// Round 12
// baseline (139.201 us; speedup 1.0000x reference)
//
#include <hip/hip_runtime.h>
#include <stdint.h>

// out[b,j] = bias[j] + sum_i [ mask*scale_base[i,j]*silu(x[b,i])
//            + mask*scale_fft[i,j]* sum_k ( cos(kx)fc0[j,i,k] + sin(kx)fc1[j,i,k] ) ]
// R12 = R11 + code motion in the K-loop: gen_feat(it+1) moved from the MFMA
//       phase into the P1 window (after DMA issue, before barrier2) so its
//       ~140 VALU cycles cover the DMA drain that barrier2 must wait on;
//       x-row preloaded to registers + full unroll (no loads in P1 chain).
// Operating point (validated R6..R11): 128x128x(K=64) tiles, KSPLIT=16,
// 32KB LDS, 4 blk/CU, single B buffer + DMA, XOR swizzle, bf16 partials.
// Lessons: no device fences in hot path (R9); no dbuf costing a block (R8);
// no VGPR clamp (R7).

#define I_DIM 256
#define O_DIM 256
#define G_DIM 32
#define B_DIM 4096

#define BM 128
#define BN 128
#define KSPLIT 16
#define ICH 16                  // i's per K-chunk
#define PITCH 72                // fallback kernel only

typedef short s8v __attribute__((ext_vector_type(8)));
typedef float f4v __attribute__((ext_vector_type(4)));

__device__ __forceinline__ uint32_t pack2bf16(float a, float b) {  // RNE
  uint32_t ua = __builtin_bit_cast(uint32_t, a);
  uint32_t ub = __builtin_bit_cast(uint32_t, b);
  ua += 0x7FFFu + ((ua >> 16) & 1u);
  ub += 0x7FFFu + ((ub >> 16) & 1u);
  return (ua >> 16) | (ub & 0xFFFF0000u);
}
__device__ __forceinline__ unsigned short bf16_rne(float a) {      // RNE scalar
  uint32_t ua = __builtin_bit_cast(uint32_t, a);
  ua += 0x7FFFu + ((ua >> 16) & 1u);
  return (unsigned short)(ua >> 16);
}
// round-half-up: ~half the insts of RNE; absmax impact negligible (R7/R8)
__device__ __forceinline__ uint32_t pack2bf16_f(float a, float b) {
  uint32_t ua = __builtin_bit_cast(uint32_t, a) + 0x8000u;
  uint32_t ub = __builtin_bit_cast(uint32_t, b) + 0x8000u;
  return (ua >> 16) | (ub & 0xFFFF0000u);
}
__device__ __forceinline__ float silu_f(float v) { return v / (1.0f + __expf(-v)); }

// cos/sin Chebyshev features k=1..32 for one (row, half): 16 packed uint32
__device__ __forceinline__ void gen_feat(float xv, int half, uint32_t* fb) {
  float s, c;
  __sincosf(xv, &s, &c);
  const float m2 = 2.f * c;
  float f0 = half ? s : c;                       // k=1
  float f1 = m2 * f0 - (half ? 0.f : 1.f);       // k=2
  fb[0] = pack2bf16_f(f0, f1);
  #pragma unroll
  for (int p = 1; p < 16; ++p) {
    float f2 = m2 * f1 - f0;
    float f3 = m2 * f2 - f1;
    fb[p] = pack2bf16_f(f2, f3);
    f0 = f2; f1 = f3;
  }
}

// ------------------------------------------------ prep: pack B, i-major, XOR-swizzled
// Bp[(i*256+j)*64 + s*8 ..] = chunk (s ^ (j&7)) of W[j,i,0:64]
// 2 threads per (i,j): d=0 -> cos chunks 0..3, d=1 -> sin chunks 4..7
__global__ __launch_bounds__(256) void prep_bs_kernel(
    const float* __restrict__ fc, const float* __restrict__ mask,
    const float* __restrict__ sfft, short* __restrict__ Bp)
{
  const int gid = blockIdx.x * 256 + threadIdx.x;   // 131072 threads
  const int p = gid >> 1, d = gid & 1;
  const int i = p >> 8, j = p & 255;
  const size_t ij = (size_t)i * O_DIM + j;
  const float sf = sfft[ij] * mask[ij];
  const float* src = fc + (size_t)d * (O_DIM * I_DIM * G_DIM)
                        + ((size_t)j * I_DIM + i) * G_DIM;
  uint32_t w[16];
  #pragma unroll
  for (int q = 0; q < 8; ++q) {
    float4 v = ((const float4*)src)[q];
    w[2*q]   = pack2bf16(v.x * sf, v.y * sf);
    w[2*q+1] = pack2bf16(v.z * sf, v.w * sf);
  }
  uint4* dst = (uint4*)(Bp + (size_t)p * 64);
  const int xr = j & 7;
  #pragma unroll
  for (int c = 0; c < 4; ++c)
    dst[(4 * d + c) ^ xr] = make_uint4(w[4*c], w[4*c+1], w[4*c+2], w[4*c+3]);
}

// ------------------------------------------------ main GEMM
__global__ __launch_bounds__(256, 4) void kan_main2(
    const float* __restrict__ x,
    const short* __restrict__ Bp,
    const float* __restrict__ mask,
    const float* __restrict__ scale_base,
    unsigned short* __restrict__ partial) // (16, 4096, 256) bf16
{
  __shared__ short A_lds[BM * 64];        // 16 KB, XOR-chunk swizzled
  __shared__ short B_lds[BN * 64];        // 16 KB, DMA image (pre-swizzled)

  const int tid = threadIdx.x;
  const int bx  = blockIdx.x;
  const int kc  = bx & 15;                // XCD affinity: Bp slice L2-resident
  const int bn  = (bx >> 4) & 1;
  const int bm  = bx >> 5;
  const int i0  = kc * ICH;

  const int lane = tid & 63;
  const int wave = tid >> 6;
  const int wm   = wave & 1;
  const int wn   = wave >> 1;
  const int l15  = lane & 15;
  const int quad = lane >> 4;

  f4v acc[4][4];
  #pragma unroll
  for (int a = 0; a < 4; ++a)
    #pragma unroll
    for (int b = 0; b < 4; ++b)
      acc[a][b] = (f4v){0.f, 0.f, 0.f, 0.f};

  const int row  = tid >> 1;
  const int half = tid & 1;
  const int mg   = bm * BM + row;
  const int jg   = bn * BN + row;
  const int xr   = row & 7;

  const float* xrow = x + (size_t)mg * I_DIM + i0;
  uint4* Arow = (uint4*)&A_lds[row * 64];
  const int c0 = half * 4;                // this thread's 4 A-chunks
  const int q0 = wave * 4;                // 4 DMA insts per wave
  const size_t dma_lane_off = (size_t)lane * 8;

  // preload this thread's 16 x-values (one cache line) into registers
  float xv[ICH];
  {
    float4 x0 = ((const float4*)xrow)[0];
    float4 x1 = ((const float4*)xrow)[1];
    float4 x2 = ((const float4*)xrow)[2];
    float4 x3 = ((const float4*)xrow)[3];
    xv[0]=x0.x; xv[1]=x0.y; xv[2]=x0.z; xv[3]=x0.w;
    xv[4]=x1.x; xv[5]=x1.y; xv[6]=x1.z; xv[7]=x1.w;
    xv[8]=x2.x; xv[9]=x2.y; xv[10]=x2.z; xv[11]=x2.w;
    xv[12]=x3.x; xv[13]=x3.y; xv[14]=x3.z; xv[15]=x3.w;
  }

  uint32_t aNext[16];
  gen_feat(xv[0], half, aNext);

  #pragma unroll
  for (int it = 0; it < ICH; ++it) {
    __syncthreads();                      // readers of it-1 done

    // P1a: A ds_writes (features made last iteration)
    Arow[(c0 + 0) ^ xr] = make_uint4(aNext[0],  aNext[1],  aNext[2],  aNext[3]);
    Arow[(c0 + 1) ^ xr] = make_uint4(aNext[4],  aNext[5],  aNext[6],  aNext[7]);
    Arow[(c0 + 2) ^ xr] = make_uint4(aNext[8],  aNext[9],  aNext[10], aNext[11]);
    Arow[(c0 + 3) ^ xr] = make_uint4(aNext[12], aNext[13], aNext[14], aNext[15]);

    // P1b: B DMA issue (after ds_writes: no alias-order stall)
    {
      const size_t rbase = ((size_t)(i0 + it) * 256 + bn * BN) * 64;
      #pragma unroll
      for (int c = 0; c < 4; ++c) {
        const int q = q0 + c;
        const short* g = Bp + rbase + (size_t)q * 8 * 64 + dma_lane_off;
        __builtin_amdgcn_global_load_lds(
            (const __attribute__((address_space(1))) void*)g,
            (__attribute__((address_space(3))) void*)&B_lds[q * 8 * 64],
            16, 0, 0);
      }
    }

    // P1c: gen_feat(it+1) HERE — its VALU work fills the DMA-drain window
    // that barrier2 must wait on anyway (R12 code motion; was after barrier2).
    if (it + 1 < ICH) gen_feat(xv[it + 1], half, aNext);

    __syncthreads();                      // drains vmcnt (DMA) + lgkm (A writes)

    // P2: pure ds_read + MFMA
    #pragma unroll
    for (int ks = 0; ks < 2; ++ks) {
      s8v a[4], b[4];
      #pragma unroll
      for (int tm = 0; tm < 4; ++tm) {
        const int r = wm * 64 + tm * 16 + l15;
        a[tm] = *(const s8v*)&A_lds[r * 64 + (((ks * 4 + quad) ^ (r & 7)) * 8)];
      }
      #pragma unroll
      for (int tn = 0; tn < 4; ++tn) {
        const int r = wn * 64 + tn * 16 + l15;
        b[tn] = *(const s8v*)&B_lds[r * 64 + (((ks * 4 + quad) ^ (r & 7)) * 8)];
      }
      #pragma unroll
      for (int tm = 0; tm < 4; ++tm)
        #pragma unroll
        for (int tn = 0; tn < 4; ++tn)
          acc[tm][tn] = __builtin_amdgcn_mfma_f32_16x16x32_bf16(a[tm], b[tn], acc[tm][tn], 0, 0, 0);
    }
  }

  // ---------------- base tile: K=32 (16 silu features + 16 zeros)
  __syncthreads();
  {
    float4 v0, v1;
    if (half == 0) { v0 = ((const float4*)xrow)[0]; v1 = ((const float4*)xrow)[1]; }
    else           { v0 = ((const float4*)xrow)[2]; v1 = ((const float4*)xrow)[3]; }
    uint32_t a0 = pack2bf16(silu_f(v0.x), silu_f(v0.y));
    uint32_t a1 = pack2bf16(silu_f(v0.z), silu_f(v0.w));
    uint32_t a2 = pack2bf16(silu_f(v1.x), silu_f(v1.y));
    uint32_t a3 = pack2bf16(silu_f(v1.z), silu_f(v1.w));
    Arow[half ^ xr]       = make_uint4(a0, a1, a2, a3);
    Arow[(2 + half) ^ xr] = make_uint4(0, 0, 0, 0);

    uint32_t w[4];
    #pragma unroll
    for (int p = 0; p < 4; ++p) {
      const int ia = i0 + half * 8 + 2 * p;
      const size_t o0 = (size_t)ia * O_DIM + jg;
      const size_t o1 = o0 + O_DIM;
      w[p] = pack2bf16(scale_base[o0] * mask[o0], scale_base[o1] * mask[o1]);
    }
    uint4* Brow = (uint4*)&B_lds[row * 64];
    Brow[half ^ xr]       = make_uint4(w[0], w[1], w[2], w[3]);
    Brow[(2 + half) ^ xr] = make_uint4(0, 0, 0, 0);
  }
  __syncthreads();
  {
    s8v a[4], b[4];
    #pragma unroll
    for (int tm = 0; tm < 4; ++tm) {
      const int r = wm * 64 + tm * 16 + l15;
      a[tm] = *(const s8v*)&A_lds[r * 64 + ((quad ^ (r & 7)) * 8)];
    }
    #pragma unroll
    for (int tn = 0; tn < 4; ++tn) {
      const int r = wn * 64 + tn * 16 + l15;
      b[tn] = *(const s8v*)&B_lds[r * 64 + ((quad ^ (r & 7)) * 8)];
    }
    #pragma unroll
    for (int tm = 0; tm < 4; ++tm)
      #pragma unroll
      for (int tn = 0; tn < 4; ++tn)
        acc[tm][tn] = __builtin_amdgcn_mfma_f32_16x16x32_bf16(a[tm], b[tn], acc[tm][tn], 0, 0, 0);
  }

  // ---------------- epilogue: coalesced bf16 partial stores (RNE, once/block)
  unsigned short* pbase = partial + (size_t)kc * B_DIM * O_DIM;
  #pragma unroll
  for (int tm = 0; tm < 4; ++tm) {
    #pragma unroll
    for (int tn = 0; tn < 4; ++tn) {
      const int n_g = bn * BN + wn * 64 + tn * 16 + l15;
      f4v v = acc[tm][tn];
      #pragma unroll
      for (int r = 0; r < 4; ++r) {
        const int m_g = bm * BM + wm * 64 + tm * 16 + quad * 4 + r;
        pbase[(size_t)m_g * O_DIM + n_g] = bf16_rne(v[r]);
      }
    }
  }
}

// ------------------------------------------------ reduce (bf16 partials)
__global__ __launch_bounds__(256) void reduce_kernel(
    const unsigned short* __restrict__ partial, const float* __restrict__ bias,
    float* __restrict__ out, int nk)
{
  const int g  = blockIdx.x * 256 + threadIdx.x;   // 262144 threads
  const int m  = g >> 6;
  const int n4 = (g & 63) << 2;
  float4 acc = ((const float4*)(bias + n4))[0];
  for (int kc = 0; kc < nk; ++kc) {
    const ushort4 v = *(const ushort4*)&partial[((size_t)kc * B_DIM + m) * O_DIM + n4];
    acc.x += __builtin_bit_cast(float, (uint32_t)v.x << 16);
    acc.y += __builtin_bit_cast(float, (uint32_t)v.y << 16);
    acc.z += __builtin_bit_cast(float, (uint32_t)v.z << 16);
    acc.w += __builtin_bit_cast(float, (uint32_t)v.w << 16);
  }
  ((float4*)(out + (size_t)m * O_DIM + n4))[0] = acc;
}

// ================================================ ws-free atomic fallback (R2)
__global__ __launch_bounds__(256, 4) void kan_fft_fallback(
    const float* __restrict__ x, const float* __restrict__ fc,
    const float* __restrict__ bias, const float* __restrict__ mask,
    const float* __restrict__ scale_base, const float* __restrict__ scale_fft,
    float* __restrict__ out)
{
  __shared__ short A_lds[BM * PITCH];
  __shared__ short B_lds[BN * PITCH];

  const int tid = threadIdx.x;
  const int bx  = blockIdx.x;
  const int kc  = bx & 15;
  const int bn  = (bx >> 4) & 1;
  const int bm  = bx >> 5;
  const int i0  = kc * ICH;

  const int lane = tid & 63;
  const int wave = tid >> 6;
  const int wm   = wave & 1;
  const int wn   = wave >> 1;
  const int l15  = lane & 15;
  const int kgrp = (lane >> 4) * 8;

  f4v acc[4][4];
  #pragma unroll
  for (int a = 0; a < 4; ++a)
    #pragma unroll
    for (int b = 0; b < 4; ++b)
      acc[a][b] = (f4v){0.f, 0.f, 0.f, 0.f};

  const int row  = tid >> 1;
  const int half = tid & 1;
  const int mg   = bm * BM + row;
  const int jg   = bn * BN + row;

  const float* xrow   = x + (size_t)mg * I_DIM + i0;
  const float* fcbase = fc + (size_t)half * (O_DIM * I_DIM * G_DIM)
                           + ((size_t)jg * I_DIM + i0) * G_DIM;
  uint32_t* Arow = (uint32_t*)&A_lds[row * PITCH + half * 32];
  uint32_t* Brow = (uint32_t*)&B_lds[row * PITCH + half * 32];

  for (int it = 0; it < ICH; ++it) {
    __syncthreads();
    {
      uint32_t fb[16];
      gen_feat(xrow[it], half, fb);
      ((uint4*)Arow)[0] = make_uint4(fb[0],  fb[1],  fb[2],  fb[3]);
      ((uint4*)Arow)[1] = make_uint4(fb[4],  fb[5],  fb[6],  fb[7]);
      ((uint4*)Arow)[2] = make_uint4(fb[8],  fb[9],  fb[10], fb[11]);
      ((uint4*)Arow)[3] = make_uint4(fb[12], fb[13], fb[14], fb[15]);
    }
    {
      const int i = i0 + it;
      const size_t ij = (size_t)i * O_DIM + jg;
      const float sf  = scale_fft[ij] * mask[ij];
      const float* src = fcbase + it * G_DIM;
      uint32_t wb[16];
      #pragma unroll
      for (int q = 0; q < 8; ++q) {
        float4 v = ((const float4*)src)[q];
        wb[2*q]   = pack2bf16(v.x * sf, v.y * sf);
        wb[2*q+1] = pack2bf16(v.z * sf, v.w * sf);
      }
      ((uint4*)Brow)[0] = make_uint4(wb[0],  wb[1],  wb[2],  wb[3]);
      ((uint4*)Brow)[1] = make_uint4(wb[4],  wb[5],  wb[6],  wb[7]);
      ((uint4*)Brow)[2] = make_uint4(wb[8],  wb[9],  wb[10], wb[11]);
      ((uint4*)Brow)[3] = make_uint4(wb[12], wb[13], wb[14], wb[15]);
    }
    __syncthreads();
    #pragma unroll
    for (int ks = 0; ks < 2; ++ks) {
      s8v a[4], b[4];
      #pragma unroll
      for (int tm = 0; tm < 4; ++tm)
        a[tm] = *(const s8v*)&A_lds[(wm * 64 + tm * 16 + l15) * PITCH + ks * 32 + kgrp];
      #pragma unroll
      for (int tn = 0; tn < 4; ++tn)
        b[tn] = *(const s8v*)&B_lds[(wn * 64 + tn * 16 + l15) * PITCH + ks * 32 + kgrp];
      #pragma unroll
      for (int tm = 0; tm < 4; ++tm)
        #pragma unroll
        for (int tn = 0; tn < 4; ++tn)
          acc[tm][tn] = __builtin_amdgcn_mfma_f32_16x16x32_bf16(a[tm], b[tn], acc[tm][tn], 0, 0, 0);
    }
  }

  __syncthreads();
  {
    const float* xb = xrow + half * 8;
    float4 v0 = ((const float4*)xb)[0];
    float4 v1 = ((const float4*)xb)[1];
    uint32_t a0 = pack2bf16(silu_f(v0.x), silu_f(v0.y));
    uint32_t a1 = pack2bf16(silu_f(v0.z), silu_f(v0.w));
    uint32_t a2 = pack2bf16(silu_f(v1.x), silu_f(v1.y));
    uint32_t a3 = pack2bf16(silu_f(v1.z), silu_f(v1.w));
    ((uint4*)&A_lds[row * PITCH + half * 8])[0]      = make_uint4(a0, a1, a2, a3);
    ((uint4*)&A_lds[row * PITCH + 16 + half * 8])[0] = make_uint4(0, 0, 0, 0);
    uint32_t w[4];
    #pragma unroll
    for (int p = 0; p < 4; ++p) {
      const int ia = i0 + half * 8 + 2 * p;
      const size_t o0 = (size_t)ia * O_DIM + jg;
      const size_t o1 = o0 + O_DIM;
      w[p] = pack2bf16(scale_base[o0] * mask[o0], scale_base[o1] * mask[o1]);
    }
    ((uint4*)&B_lds[row * PITCH + half * 8])[0]      = make_uint4(w[0], w[1], w[2], w[3]);
    ((uint4*)&B_lds[row * PITCH + 16 + half * 8])[0] = make_uint4(0, 0, 0, 0);
  }
  __syncthreads();
  {
    s8v a[4], b[4];
    #pragma unroll
    for (int tm = 0; tm < 4; ++tm)
      a[tm] = *(const s8v*)&A_lds[(wm * 64 + tm * 16 + l15) * PITCH + kgrp];
    #pragma unroll
    for (int tn = 0; tn < 4; ++tn)
      b[tn] = *(const s8v*)&B_lds[(wn * 64 + tn * 16 + l15) * PITCH + kgrp];
    #pragma unroll
    for (int tm = 0; tm < 4; ++tm)
      #pragma unroll
      for (int tn = 0; tn < 4; ++tn)
        acc[tm][tn] = __builtin_amdgcn_mfma_f32_16x16x32_bf16(a[tm], b[tn], acc[tm][tn], 0, 0, 0);
  }

  const int quad = lane >> 4;
  #pragma unroll
  for (int tm = 0; tm < 4; ++tm) {
    #pragma unroll
    for (int tn = 0; tn < 4; ++tn) {
      const int n_g = bn * BN + wn * 64 + tn * 16 + l15;
      f4v v = acc[tm][tn];
      #pragma unroll
      for (int r = 0; r < 4; ++r) {
        const int m_g = bm * BM + wm * 64 + tm * 16 + quad * 4 + r;
        float val = v[r];
        if (kc == 0) val += bias[n_g];
        atomicAdd(&out[(size_t)m_g * O_DIM + n_g], val);
      }
    }
  }
}

extern "C" void kernel_launch(void* const* d_in, const int* in_sizes, int n_in,
                              void* d_out, int out_size, void* d_ws, size_t ws_size,
                              hipStream_t stream) {
  const float* x          = (const float*)d_in[0];
  const float* fc         = (const float*)d_in[1];
  const float* bias       = (const float*)d_in[2];
  const float* mask       = (const float*)d_in[3];
  const float* scale_base = (const float*)d_in[4];
  const float* scale_fft  = (const float*)d_in[5];
  float* out = (float*)d_out;

  const size_t BP_B    = (size_t)I_DIM * O_DIM * 64 * 2;        //  8,388,608
  const size_t PARTH_B = (size_t)KSPLIT * B_DIM * O_DIM * 2;    // 33,554,432

  if (ws_size >= BP_B + PARTH_B) {
    short*          Bp      = (short*)d_ws;
    unsigned short* partial = (unsigned short*)((char*)d_ws + BP_B);
    prep_bs_kernel<<<dim3(512), dim3(256), 0, stream>>>(fc, mask, scale_fft, Bp);
    kan_main2<<<dim3(1024), dim3(256), 0, stream>>>(x, Bp, mask, scale_base, partial);
    reduce_kernel<<<dim3(1024), dim3(256), 0, stream>>>(partial, bias, out, KSPLIT);
  } else {
    hipMemsetAsync(d_out, 0, (size_t)out_size * sizeof(float), stream);
    kan_fft_fallback<<<dim3(1024), dim3(256), 0, stream>>>(
        x, fc, bias, mask, scale_base, scale_fft, out);
  }
}

// Round 13
// 132.929 us; speedup vs baseline: 1.0472x; 1.0472x over previous
//
#include <hip/hip_runtime.h>
#include <stdint.h>

// out[b,j] = bias[j] + sum_i [ mask*scale_base[i,j]*silu(x[b,i])
//            + mask*scale_fft[i,j]* sum_k ( cos(kx)fc0[j,i,k] + sin(kx)fc1[j,i,k] ) ]
// R13 = exact revert to R11 (best measured: total 133.4 us, main 51.1 us).
// Operating point (validated R6/R10/R11): 128x128x(K=64) tiles, KSPLIT=16,
// 32KB LDS, 4 blk/CU, single B buffer via global_load_lds from pre-XOR-swizzled
// pack, A XOR-swizzle, fast bf16 pack in gen_feat, bf16 partials + reduce.
// Failed escapes (do not retry): R7 VGPR clamp (spill), R8 B-dbuf (-1 block),
// R9 device fences (L2 inv), R12 full unroll + x-preload (scratch spill).

#define I_DIM 256
#define O_DIM 256
#define G_DIM 32
#define B_DIM 4096

#define BM 128
#define BN 128
#define KSPLIT 16
#define ICH 16                  // i's per K-chunk
#define PITCH 72                // fallback kernel only

typedef short s8v __attribute__((ext_vector_type(8)));
typedef float f4v __attribute__((ext_vector_type(4)));

__device__ __forceinline__ uint32_t pack2bf16(float a, float b) {  // RNE
  uint32_t ua = __builtin_bit_cast(uint32_t, a);
  uint32_t ub = __builtin_bit_cast(uint32_t, b);
  ua += 0x7FFFu + ((ua >> 16) & 1u);
  ub += 0x7FFFu + ((ub >> 16) & 1u);
  return (ua >> 16) | (ub & 0xFFFF0000u);
}
__device__ __forceinline__ unsigned short bf16_rne(float a) {      // RNE scalar
  uint32_t ua = __builtin_bit_cast(uint32_t, a);
  ua += 0x7FFFu + ((ua >> 16) & 1u);
  return (unsigned short)(ua >> 16);
}
// round-half-up: ~half the insts of RNE; absmax impact negligible (R7/R8)
__device__ __forceinline__ uint32_t pack2bf16_f(float a, float b) {
  uint32_t ua = __builtin_bit_cast(uint32_t, a) + 0x8000u;
  uint32_t ub = __builtin_bit_cast(uint32_t, b) + 0x8000u;
  return (ua >> 16) | (ub & 0xFFFF0000u);
}
__device__ __forceinline__ float silu_f(float v) { return v / (1.0f + __expf(-v)); }

// cos/sin Chebyshev features k=1..32 for one (row, half): 16 packed uint32
__device__ __forceinline__ void gen_feat(float xv, int half, uint32_t* fb) {
  float s, c;
  __sincosf(xv, &s, &c);
  const float m2 = 2.f * c;
  float f0 = half ? s : c;                       // k=1
  float f1 = m2 * f0 - (half ? 0.f : 1.f);       // k=2
  fb[0] = pack2bf16_f(f0, f1);
  #pragma unroll
  for (int p = 1; p < 16; ++p) {
    float f2 = m2 * f1 - f0;
    float f3 = m2 * f2 - f1;
    fb[p] = pack2bf16_f(f2, f3);
    f0 = f2; f1 = f3;
  }
}

// ------------------------------------------------ prep: pack B, i-major, XOR-swizzled
// Bp[(i*256+j)*64 + s*8 ..] = chunk (s ^ (j&7)) of W[j,i,0:64]
// 2 threads per (i,j): d=0 -> cos chunks 0..3, d=1 -> sin chunks 4..7
__global__ __launch_bounds__(256) void prep_bs_kernel(
    const float* __restrict__ fc, const float* __restrict__ mask,
    const float* __restrict__ sfft, short* __restrict__ Bp)
{
  const int gid = blockIdx.x * 256 + threadIdx.x;   // 131072 threads
  const int p = gid >> 1, d = gid & 1;
  const int i = p >> 8, j = p & 255;
  const size_t ij = (size_t)i * O_DIM + j;
  const float sf = sfft[ij] * mask[ij];
  const float* src = fc + (size_t)d * (O_DIM * I_DIM * G_DIM)
                        + ((size_t)j * I_DIM + i) * G_DIM;
  uint32_t w[16];
  #pragma unroll
  for (int q = 0; q < 8; ++q) {
    float4 v = ((const float4*)src)[q];
    w[2*q]   = pack2bf16(v.x * sf, v.y * sf);
    w[2*q+1] = pack2bf16(v.z * sf, v.w * sf);
  }
  uint4* dst = (uint4*)(Bp + (size_t)p * 64);
  const int xr = j & 7;
  #pragma unroll
  for (int c = 0; c < 4; ++c)
    dst[(4 * d + c) ^ xr] = make_uint4(w[4*c], w[4*c+1], w[4*c+2], w[4*c+3]);
}

// ------------------------------------------------ main GEMM
__global__ __launch_bounds__(256, 4) void kan_main2(
    const float* __restrict__ x,
    const short* __restrict__ Bp,
    const float* __restrict__ mask,
    const float* __restrict__ scale_base,
    unsigned short* __restrict__ partial) // (16, 4096, 256) bf16
{
  __shared__ short A_lds[BM * 64];        // 16 KB, XOR-chunk swizzled
  __shared__ short B_lds[BN * 64];        // 16 KB, DMA image (pre-swizzled)

  const int tid = threadIdx.x;
  const int bx  = blockIdx.x;
  const int kc  = bx & 15;                // XCD affinity: Bp slice L2-resident
  const int bn  = (bx >> 4) & 1;
  const int bm  = bx >> 5;
  const int i0  = kc * ICH;

  const int lane = tid & 63;
  const int wave = tid >> 6;
  const int wm   = wave & 1;
  const int wn   = wave >> 1;
  const int l15  = lane & 15;
  const int quad = lane >> 4;

  f4v acc[4][4];
  #pragma unroll
  for (int a = 0; a < 4; ++a)
    #pragma unroll
    for (int b = 0; b < 4; ++b)
      acc[a][b] = (f4v){0.f, 0.f, 0.f, 0.f};

  const int row  = tid >> 1;
  const int half = tid & 1;
  const int mg   = bm * BM + row;
  const int jg   = bn * BN + row;
  const int xr   = row & 7;

  const float* xrow = x + (size_t)mg * I_DIM + i0;
  uint4* Arow = (uint4*)&A_lds[row * 64];
  const int c0 = half * 4;                // this thread's 4 A-chunks
  const int q0 = wave * 4;                // 4 DMA insts per wave
  const size_t dma_lane_off = (size_t)lane * 8;

  uint32_t aNext[16];
  gen_feat(xrow[0], half, aNext);

  for (int it = 0; it < ICH; ++it) {
    __syncthreads();                      // readers of it-1 done

    // A: store regs generated during previous MFMA phase (swizzled slots)
    Arow[(c0 + 0) ^ xr] = make_uint4(aNext[0],  aNext[1],  aNext[2],  aNext[3]);
    Arow[(c0 + 1) ^ xr] = make_uint4(aNext[4],  aNext[5],  aNext[6],  aNext[7]);
    Arow[(c0 + 2) ^ xr] = make_uint4(aNext[8],  aNext[9],  aNext[10], aNext[11]);
    Arow[(c0 + 3) ^ xr] = make_uint4(aNext[12], aNext[13], aNext[14], aNext[15]);

    // B: direct HBM/L2 -> LDS DMA (after ds_writes: no alias-order stall).
    // One inst = 64 lanes x 16B = 1KB = 8 rows; 16 insts tile BN=128 rows.
    {
      const size_t rbase = ((size_t)(i0 + it) * 256 + bn * BN) * 64;
      #pragma unroll
      for (int c = 0; c < 4; ++c) {
        const int q = q0 + c;
        const short* g = Bp + rbase + (size_t)q * 8 * 64 + dma_lane_off;
        __builtin_amdgcn_global_load_lds(
            (const __attribute__((address_space(1))) void*)g,
            (__attribute__((address_space(3))) void*)&B_lds[q * 8 * 64],
            16, 0, 0);
      }
    }

    __syncthreads();                      // drains vmcnt (DMA) + lgkm (A writes)

    if (it + 1 < ICH) gen_feat(xrow[it + 1], half, aNext);  // overlaps MFMA below

    #pragma unroll
    for (int ks = 0; ks < 2; ++ks) {
      s8v a[4], b[4];
      #pragma unroll
      for (int tm = 0; tm < 4; ++tm) {
        const int r = wm * 64 + tm * 16 + l15;
        a[tm] = *(const s8v*)&A_lds[r * 64 + (((ks * 4 + quad) ^ (r & 7)) * 8)];
      }
      #pragma unroll
      for (int tn = 0; tn < 4; ++tn) {
        const int r = wn * 64 + tn * 16 + l15;
        b[tn] = *(const s8v*)&B_lds[r * 64 + (((ks * 4 + quad) ^ (r & 7)) * 8)];
      }
      #pragma unroll
      for (int tm = 0; tm < 4; ++tm)
        #pragma unroll
        for (int tn = 0; tn < 4; ++tn)
          acc[tm][tn] = __builtin_amdgcn_mfma_f32_16x16x32_bf16(a[tm], b[tn], acc[tm][tn], 0, 0, 0);
    }
  }

  // ---------------- base tile: K=32 (16 silu features + 16 zeros)
  __syncthreads();
  {
    const float* xb = xrow + half * 8;
    float4 v0 = ((const float4*)xb)[0];
    float4 v1 = ((const float4*)xb)[1];
    uint32_t a0 = pack2bf16(silu_f(v0.x), silu_f(v0.y));
    uint32_t a1 = pack2bf16(silu_f(v0.z), silu_f(v0.w));
    uint32_t a2 = pack2bf16(silu_f(v1.x), silu_f(v1.y));
    uint32_t a3 = pack2bf16(silu_f(v1.z), silu_f(v1.w));
    Arow[half ^ xr]       = make_uint4(a0, a1, a2, a3);
    Arow[(2 + half) ^ xr] = make_uint4(0, 0, 0, 0);

    uint32_t w[4];
    #pragma unroll
    for (int p = 0; p < 4; ++p) {
      const int ia = i0 + half * 8 + 2 * p;
      const size_t o0 = (size_t)ia * O_DIM + jg;
      const size_t o1 = o0 + O_DIM;
      w[p] = pack2bf16(scale_base[o0] * mask[o0], scale_base[o1] * mask[o1]);
    }
    uint4* Brow = (uint4*)&B_lds[row * 64];
    Brow[half ^ xr]       = make_uint4(w[0], w[1], w[2], w[3]);
    Brow[(2 + half) ^ xr] = make_uint4(0, 0, 0, 0);
  }
  __syncthreads();
  {
    s8v a[4], b[4];
    #pragma unroll
    for (int tm = 0; tm < 4; ++tm) {
      const int r = wm * 64 + tm * 16 + l15;
      a[tm] = *(const s8v*)&A_lds[r * 64 + ((quad ^ (r & 7)) * 8)];
    }
    #pragma unroll
    for (int tn = 0; tn < 4; ++tn) {
      const int r = wn * 64 + tn * 16 + l15;
      b[tn] = *(const s8v*)&B_lds[r * 64 + ((quad ^ (r & 7)) * 8)];
    }
    #pragma unroll
    for (int tm = 0; tm < 4; ++tm)
      #pragma unroll
      for (int tn = 0; tn < 4; ++tn)
        acc[tm][tn] = __builtin_amdgcn_mfma_f32_16x16x32_bf16(a[tm], b[tn], acc[tm][tn], 0, 0, 0);
  }

  // ---------------- epilogue: coalesced bf16 partial stores (RNE, once/block)
  unsigned short* pbase = partial + (size_t)kc * B_DIM * O_DIM;
  #pragma unroll
  for (int tm = 0; tm < 4; ++tm) {
    #pragma unroll
    for (int tn = 0; tn < 4; ++tn) {
      const int n_g = bn * BN + wn * 64 + tn * 16 + l15;
      f4v v = acc[tm][tn];
      #pragma unroll
      for (int r = 0; r < 4; ++r) {
        const int m_g = bm * BM + wm * 64 + tm * 16 + quad * 4 + r;
        pbase[(size_t)m_g * O_DIM + n_g] = bf16_rne(v[r]);
      }
    }
  }
}

// ------------------------------------------------ reduce (bf16 partials)
__global__ __launch_bounds__(256) void reduce_kernel(
    const unsigned short* __restrict__ partial, const float* __restrict__ bias,
    float* __restrict__ out, int nk)
{
  const int g  = blockIdx.x * 256 + threadIdx.x;   // 262144 threads
  const int m  = g >> 6;
  const int n4 = (g & 63) << 2;
  float4 acc = ((const float4*)(bias + n4))[0];
  for (int kc = 0; kc < nk; ++kc) {
    const ushort4 v = *(const ushort4*)&partial[((size_t)kc * B_DIM + m) * O_DIM + n4];
    acc.x += __builtin_bit_cast(float, (uint32_t)v.x << 16);
    acc.y += __builtin_bit_cast(float, (uint32_t)v.y << 16);
    acc.z += __builtin_bit_cast(float, (uint32_t)v.z << 16);
    acc.w += __builtin_bit_cast(float, (uint32_t)v.w << 16);
  }
  ((float4*)(out + (size_t)m * O_DIM + n4))[0] = acc;
}

// ================================================ ws-free atomic fallback (R2)
__global__ __launch_bounds__(256, 4) void kan_fft_fallback(
    const float* __restrict__ x, const float* __restrict__ fc,
    const float* __restrict__ bias, const float* __restrict__ mask,
    const float* __restrict__ scale_base, const float* __restrict__ scale_fft,
    float* __restrict__ out)
{
  __shared__ short A_lds[BM * PITCH];
  __shared__ short B_lds[BN * PITCH];

  const int tid = threadIdx.x;
  const int bx  = blockIdx.x;
  const int kc  = bx & 15;
  const int bn  = (bx >> 4) & 1;
  const int bm  = bx >> 5;
  const int i0  = kc * ICH;

  const int lane = tid & 63;
  const int wave = tid >> 6;
  const int wm   = wave & 1;
  const int wn   = wave >> 1;
  const int l15  = lane & 15;
  const int kgrp = (lane >> 4) * 8;

  f4v acc[4][4];
  #pragma unroll
  for (int a = 0; a < 4; ++a)
    #pragma unroll
    for (int b = 0; b < 4; ++b)
      acc[a][b] = (f4v){0.f, 0.f, 0.f, 0.f};

  const int row  = tid >> 1;
  const int half = tid & 1;
  const int mg   = bm * BM + row;
  const int jg   = bn * BN + row;

  const float* xrow   = x + (size_t)mg * I_DIM + i0;
  const float* fcbase = fc + (size_t)half * (O_DIM * I_DIM * G_DIM)
                           + ((size_t)jg * I_DIM + i0) * G_DIM;
  uint32_t* Arow = (uint32_t*)&A_lds[row * PITCH + half * 32];
  uint32_t* Brow = (uint32_t*)&B_lds[row * PITCH + half * 32];

  for (int it = 0; it < ICH; ++it) {
    __syncthreads();
    {
      uint32_t fb[16];
      gen_feat(xrow[it], half, fb);
      ((uint4*)Arow)[0] = make_uint4(fb[0],  fb[1],  fb[2],  fb[3]);
      ((uint4*)Arow)[1] = make_uint4(fb[4],  fb[5],  fb[6],  fb[7]);
      ((uint4*)Arow)[2] = make_uint4(fb[8],  fb[9],  fb[10], fb[11]);
      ((uint4*)Arow)[3] = make_uint4(fb[12], fb[13], fb[14], fb[15]);
    }
    {
      const int i = i0 + it;
      const size_t ij = (size_t)i * O_DIM + jg;
      const float sf  = scale_fft[ij] * mask[ij];
      const float* src = fcbase + it * G_DIM;
      uint32_t wb[16];
      #pragma unroll
      for (int q = 0; q < 8; ++q) {
        float4 v = ((const float4*)src)[q];
        wb[2*q]   = pack2bf16(v.x * sf, v.y * sf);
        wb[2*q+1] = pack2bf16(v.z * sf, v.w * sf);
      }
      ((uint4*)Brow)[0] = make_uint4(wb[0],  wb[1],  wb[2],  wb[3]);
      ((uint4*)Brow)[1] = make_uint4(wb[4],  wb[5],  wb[6],  wb[7]);
      ((uint4*)Brow)[2] = make_uint4(wb[8],  wb[9],  wb[10], wb[11]);
      ((uint4*)Brow)[3] = make_uint4(wb[12], wb[13], wb[14], wb[15]);
    }
    __syncthreads();
    #pragma unroll
    for (int ks = 0; ks < 2; ++ks) {
      s8v a[4], b[4];
      #pragma unroll
      for (int tm = 0; tm < 4; ++tm)
        a[tm] = *(const s8v*)&A_lds[(wm * 64 + tm * 16 + l15) * PITCH + ks * 32 + kgrp];
      #pragma unroll
      for (int tn = 0; tn < 4; ++tn)
        b[tn] = *(const s8v*)&B_lds[(wn * 64 + tn * 16 + l15) * PITCH + ks * 32 + kgrp];
      #pragma unroll
      for (int tm = 0; tm < 4; ++tm)
        #pragma unroll
        for (int tn = 0; tn < 4; ++tn)
          acc[tm][tn] = __builtin_amdgcn_mfma_f32_16x16x32_bf16(a[tm], b[tn], acc[tm][tn], 0, 0, 0);
    }
  }

  __syncthreads();
  {
    const float* xb = xrow + half * 8;
    float4 v0 = ((const float4*)xb)[0];
    float4 v1 = ((const float4*)xb)[1];
    uint32_t a0 = pack2bf16(silu_f(v0.x), silu_f(v0.y));
    uint32_t a1 = pack2bf16(silu_f(v0.z), silu_f(v0.w));
    uint32_t a2 = pack2bf16(silu_f(v1.x), silu_f(v1.y));
    uint32_t a3 = pack2bf16(silu_f(v1.z), silu_f(v1.w));
    ((uint4*)&A_lds[row * PITCH + half * 8])[0]      = make_uint4(a0, a1, a2, a3);
    ((uint4*)&A_lds[row * PITCH + 16 + half * 8])[0] = make_uint4(0, 0, 0, 0);
    uint32_t w[4];
    #pragma unroll
    for (int p = 0; p < 4; ++p) {
      const int ia = i0 + half * 8 + 2 * p;
      const size_t o0 = (size_t)ia * O_DIM + jg;
      const size_t o1 = o0 + O_DIM;
      w[p] = pack2bf16(scale_base[o0] * mask[o0], scale_base[o1] * mask[o1]);
    }
    ((uint4*)&B_lds[row * PITCH + half * 8])[0]      = make_uint4(w[0], w[1], w[2], w[3]);
    ((uint4*)&B_lds[row * PITCH + 16 + half * 8])[0] = make_uint4(0, 0, 0, 0);
  }
  __syncthreads();
  {
    s8v a[4], b[4];
    #pragma unroll
    for (int tm = 0; tm < 4; ++tm)
      a[tm] = *(const s8v*)&A_lds[(wm * 64 + tm * 16 + l15) * PITCH + kgrp];
    #pragma unroll
    for (int tn = 0; tn < 4; ++tn)
      b[tn] = *(const s8v*)&B_lds[(wn * 64 + tn * 16 + l15) * PITCH + kgrp];
    #pragma unroll
    for (int tm = 0; tm < 4; ++tm)
      #pragma unroll
      for (int tn = 0; tn < 4; ++tn)
        acc[tm][tn] = __builtin_amdgcn_mfma_f32_16x16x32_bf16(a[tm], b[tn], acc[tm][tn], 0, 0, 0);
  }

  const int quad = lane >> 4;
  #pragma unroll
  for (int tm = 0; tm < 4; ++tm) {
    #pragma unroll
    for (int tn = 0; tn < 4; ++tn) {
      const int n_g = bn * BN + wn * 64 + tn * 16 + l15;
      f4v v = acc[tm][tn];
      #pragma unroll
      for (int r = 0; r < 4; ++r) {
        const int m_g = bm * BM + wm * 64 + tm * 16 + quad * 4 + r;
        float val = v[r];
        if (kc == 0) val += bias[n_g];
        atomicAdd(&out[(size_t)m_g * O_DIM + n_g], val);
      }
    }
  }
}

extern "C" void kernel_launch(void* const* d_in, const int* in_sizes, int n_in,
                              void* d_out, int out_size, void* d_ws, size_t ws_size,
                              hipStream_t stream) {
  const float* x          = (const float*)d_in[0];
  const float* fc         = (const float*)d_in[1];
  const float* bias       = (const float*)d_in[2];
  const float* mask       = (const float*)d_in[3];
  const float* scale_base = (const float*)d_in[4];
  const float* scale_fft  = (const float*)d_in[5];
  float* out = (float*)d_out;

  const size_t BP_B    = (size_t)I_DIM * O_DIM * 64 * 2;        //  8,388,608
  const size_t PARTH_B = (size_t)KSPLIT * B_DIM * O_DIM * 2;    // 33,554,432

  if (ws_size >= BP_B + PARTH_B) {
    short*          Bp      = (short*)d_ws;
    unsigned short* partial = (unsigned short*)((char*)d_ws + BP_B);
    prep_bs_kernel<<<dim3(512), dim3(256), 0, stream>>>(fc, mask, scale_fft, Bp);
    kan_main2<<<dim3(1024), dim3(256), 0, stream>>>(x, Bp, mask, scale_base, partial);
    reduce_kernel<<<dim3(1024), dim3(256), 0, stream>>>(partial, bias, out, KSPLIT);
  } else {
    hipMemsetAsync(d_out, 0, (size_t)out_size * sizeof(float), stream);
    kan_fft_fallback<<<dim3(1024), dim3(256), 0, stream>>>(
        x, fc, bias, mask, scale_base, scale_fft, out);
  }
}